// Round 1
// baseline (1624.774 us; speedup 1.0000x reference)
//
#include <hip/hip_runtime.h>

#define T_LEN 1024
#define NT    1023   // T-1 steps

// ---------- helpers ----------

__device__ __forceinline__ float fast_tanh(float x) {
  // tanh(x) = 1 - 2/(exp2(x*2/ln2)+1); saturates correctly at +-inf
  float e = __builtin_amdgcn_exp2f(x * 2.8853900817779268f);
  float r = __builtin_amdgcn_rcpf(e + 1.0f);
  return fmaf(-2.0f, r, 1.0f);
}

// lane ^ K within each 32-lane group (direction-free), K in [0,31]
template <int K>
__device__ __forceinline__ float swz_xor(float v) {
  if constexpr (K == 0) {
    return v;
  } else {
    return __int_as_float(
        __builtin_amdgcn_ds_swizzle(__float_as_int(v), (K << 10) | 0x1F));
  }
}

// v += rotate-within-16(v) by S  (any rotate direction sums correctly)
template <int S>
__device__ __forceinline__ float dpp_ror_add(float v) {
  int t = __builtin_amdgcn_update_dpp(0, __float_as_int(v), 0x120 | S, 0xF, 0xF,
                                      false);
  return v + __int_as_float(t);
}

// full sum over each 32-lane group, replicated to every lane of the group
__device__ __forceinline__ float reduce32(float v) {
  v = dpp_ror_add<8>(v);
  v = dpp_ror_add<4>(v);
  v = dpp_ror_add<2>(v);
  v = dpp_ror_add<1>(v);
  int t = __builtin_amdgcn_ds_swizzle(__float_as_int(v), (16 << 10) | 0x1F);
  return v + __int_as_float(t);
}

// unrolled 32-step xor-broadcast matvec; w indexed only by template constants
template <int K>
__device__ __forceinline__ void mat_steps(float x, const float (&w)[32],
                                          float& a0, float& a1, float& a2,
                                          float& a3) {
  float s = swz_xor<K>(x);
  if constexpr ((K & 3) == 0) a0 = fmaf(w[K], s, a0);
  else if constexpr ((K & 3) == 1) a1 = fmaf(w[K], s, a1);
  else if constexpr ((K & 3) == 2) a2 = fmaf(w[K], s, a2);
  else a3 = fmaf(w[K], s, a3);
  if constexpr (K < 31) mat_steps<K + 1>(x, w, a0, a1, a2, a3);
}

// ---------- kernel ----------
// One batch element per 64-lane wave.
// lanes 0..31  : row r of the reward module  (state sr[r])
// lanes 32..63 : row r of the action module  (state sa[r])

__global__ __launch_bounds__(256, 4) void memann_kernel(
    const int* __restrict__ actions, const float* __restrict__ rewards,
    const float* __restrict__ w_r1, const float* __restrict__ b_r1,
    const float* __restrict__ w_r2, const float* __restrict__ b_r2,
    const float* __restrict__ w_a1, const float* __restrict__ b_a1,
    const float* __restrict__ w_a2, const float* __restrict__ b_a2,
    float* __restrict__ out) {
  const int tid = blockIdx.x * blockDim.x + threadIdx.x;
  const int b = tid >> 6;              // wave index == batch element
  const int lane = threadIdx.x & 63;
  const int r = lane & 31;             // row within module
  const bool hi = lane >= 32;          // high half = action module

  // ---- per-lane weight gather (one-time; weights are tiny & cached) ----
  // main 32x32 recurrent block, xor-permuted for the swizzle broadcasts
  const float* Wrow = hi ? (w_a1 + r * 36 + 4) : (w_r1 + r * 33 + 1);
  float w[32];
#pragma unroll
  for (int k = 0; k < 32; ++k) w[k] = Wrow[r ^ k];

  const float wr0 = hi ? 0.0f : w_r1[r * 33];  // reward-input column
  float wc[4];                                  // one-hot columns (action mod)
#pragma unroll
  for (int k = 0; k < 4; ++k) wc[k] = hi ? w_a1[r * 36 + k] : 0.0f;
  const float bias = hi ? b_a1[r] : b_r1[r];

  // reduction coefficients: chain P packs q_new (low) with c0 (high)
  const float coefP = hi ? w_a2[r] : w_r2[r];
  float coefC[3];
#pragma unroll
  for (int k = 0; k < 3; ++k) coefC[k] = hi ? w_a2[(k + 1) * 32 + r] : 0.0f;

  const float br2 = b_r2[0];
  float ba2[4];
#pragma unroll
  for (int k = 0; k < 4; ++k) ba2[k] = b_a2[k];

  const int* __restrict__ act_b = actions + (size_t)b * T_LEN;
  const float* __restrict__ rew_b = rewards + (size_t)b * T_LEN;
  float4* __restrict__ outq = (float4*)out + (size_t)b * NT;

  // ---- state ----
  float x = 0.0f;                       // sr[r] (low) / sa[r] (high)
  float q0 = 0.f, q1 = 0.f, q2 = 0.f, q3 = 0.f;  // replicated q (valid in hi)

  for (int t0 = 0; t0 < NT; t0 += 32) {
    // stage 32 timesteps of (action, reward) into registers
    int a_chunk = act_b[t0 + r];
    float r_chunk = rew_b[t0 + r];
    const int nstep = (NT - t0) < 32 ? (NT - t0) : 32;
    for (int tt = 0; tt < nstep; ++tt) {
      const int a_prev = __builtin_amdgcn_readlane(a_chunk, tt);
      const float r_prev = __int_as_float(
          __builtin_amdgcn_readlane(__float_as_int(r_chunk), tt));

      // ---- fused matvec: low = W_r1s @ sr, high = W_a1s @ sa ----
      float acc0 = fmaf(wr0, r_prev, bias);
      float acc1 = (a_prev == 0)   ? wc[0]
                   : (a_prev == 1) ? wc[1]
                   : (a_prev == 2) ? wc[2]
                                   : wc[3];
      float acc2 = 0.0f, acc3 = 0.0f;
      mat_steps<0>(x, w, acc0, acc1, acc2, acc3);
      const float xn = fast_tanh((acc0 + acc2) + (acc1 + acc3));

      // ---- reductions: q_new (low group) / c0..c3 (high group) ----
      const float vP = reduce32(coefP * xn);      // low: q_raw, high: c0
      const float v1 = reduce32(coefC[0] * xn);   // high: c1
      const float v2 = reduce32(coefC[1] * xn);   // high: c2
      const float v3 = reduce32(coefC[2] * xn);   // high: c3

      // bring q_raw to the high half (low half result is ignored there)
      const float qx = __shfl_xor(vP, 32, 64);
      const float qn = qx + br2;

      // ---- q decay + chosen-arm update (valid in high lanes) ----
      q0 = (a_prev == 0) ? qn : q0 * 0.95f;
      q1 = (a_prev == 1) ? qn : q1 * 0.95f;
      q2 = (a_prev == 2) ? qn : q2 * 0.95f;
      q3 = (a_prev == 3) ? qn : q3 * 0.95f;

      if (lane == 32) {
        float4 L;
        L.x = q0 + vP + ba2[0];
        L.y = q1 + v1 + ba2[1];
        L.z = q2 + v2 + ba2[2];
        L.w = q3 + v3 + ba2[3];
        outq[t0 + tt] = L;
      }
      x = xn;
    }
  }
}

// ---------- launch ----------

extern "C" void kernel_launch(void* const* d_in, const int* in_sizes, int n_in,
                              void* d_out, int out_size, void* d_ws,
                              size_t ws_size, hipStream_t stream) {
  const int* actions = (const int*)d_in[0];
  const float* rewards = (const float*)d_in[1];
  const float* w_r1 = (const float*)d_in[2];
  const float* b_r1 = (const float*)d_in[3];
  const float* w_r2 = (const float*)d_in[4];
  const float* b_r2 = (const float*)d_in[5];
  const float* w_a1 = (const float*)d_in[6];
  const float* b_a1 = (const float*)d_in[7];
  const float* w_a2 = (const float*)d_in[8];
  const float* b_a2 = (const float*)d_in[9];
  float* out = (float*)d_out;

  const int B = in_sizes[0] / T_LEN;     // 8192
  const int threads = 256;               // 4 waves/block, 1 batch elem/wave
  const int blocks = (B * 64) / threads; // 2048

  hipLaunchKernelGGL(memann_kernel, dim3(blocks), dim3(threads), 0, stream,
                     actions, rewards, w_r1, b_r1, w_r2, b_r2, w_a1, b_a1,
                     w_a2, b_a2, out);
}

// Round 2
// 1386.382 us; speedup vs baseline: 1.1720x; 1.1720x over previous
//
#include <hip/hip_runtime.h>

#define T_LEN 1024
#define NT    1023   // T-1 steps

// ---------- helpers ----------

__device__ __forceinline__ float fast_tanh(float x) {
  // tanh(x) = 1 - 2/(exp2(x*2/ln2)+1)
  float e = __builtin_amdgcn_exp2f(x * 2.8853900817779268f);
  float r = __builtin_amdgcn_rcpf(e + 1.0f);
  return fmaf(-2.0f, r, 1.0f);
}

// lane ^ K within each 32-lane group, K in [1,16] (round-0-proven pattern)
template <int K>
__device__ __forceinline__ float swz_xor(float v) {
  return __int_as_float(
      __builtin_amdgcn_ds_swizzle(__float_as_int(v), (K << 10) | 0x1F));
}

// sum over each 32-lane group, broadcast to every lane of the group
__device__ __forceinline__ float reduce32b(float v) {
  v += swz_xor<1>(v);
  v += swz_xor<2>(v);
  v += swz_xor<4>(v);
  v += swz_xor<8>(v);
  v += swz_xor<16>(v);
  return v;
}

// DPP-fused rotate+FMA: accY += ror16(x)*wy[K]; accZ += ror16(z)*wz[K].
// DPP reads only x/z (written many instrs earlier); acc pairs alternate so
// each acc has a >=2-instruction gap between write and next use.
#define MV_ROR(aY, aZ, K)                                                \
  asm volatile("v_fmac_f32 %0, %2, %3 row_ror:" #K "\n\t"                \
               "v_fmac_f32 %1, %4, %5 row_ror:" #K                       \
               : "+v"(aY), "+v"(aZ)                                      \
               : "v"(x), "v"(wy[K]), "v"(z), "v"(wz[K]))

// ---------- kernel ----------
// One batch element per 64-lane wave.
// lanes 0..31  : row r of the reward module  (state sr[r])
// lanes 32..63 : row r of the action module  (state sa[r])

__global__ __launch_bounds__(256, 4) void memann_kernel(
    const int* __restrict__ actions, const float* __restrict__ rewards,
    const float* __restrict__ w_r1, const float* __restrict__ b_r1,
    const float* __restrict__ w_r2, const float* __restrict__ b_r2,
    const float* __restrict__ w_a1, const float* __restrict__ b_a1,
    const float* __restrict__ w_a2, const float* __restrict__ b_a2,
    float* __restrict__ out) {
  const int tid = blockIdx.x * blockDim.x + threadIdx.x;
  const int b = tid >> 6;              // wave index == batch element
  const int lane = threadIdx.x & 63;
  const int r = lane & 31;             // row within module
  const bool hi = lane >= 32;          // high half = action module

  // ---- LDS table for the one-hot column of w_a1 (low lanes read zeros) ----
  __shared__ float lds_wc[256];        // [action][lane]: hi -> w_a1 col, lo -> 0
  {
    const int i = threadIdx.x;         // blockDim.x == 256
    const int a = i >> 6, l = i & 63;
    lds_wc[i] = (l >= 32) ? w_a1[(l - 32) * 36 + a] : 0.0f;
  }
  __syncthreads();

  // ---- runtime probe of DPP row_ror direction (direction-proof weights) ----
  const int posi = r & 15;
  int pr;
  asm volatile("s_nop 1\n\tv_mov_b32 %0, %1 row_ror:1" : "=v"(pr) : "v"(posi));
  const int srcoff = __builtin_amdgcn_readlane(pr, 0) & 15;  // 1 or 15

  // ---- per-lane weight gather, permuted for row_ror broadcasts ----
  const int row = (r >> 4) & 1;
  const float* Wrow = hi ? (w_a1 + r * 36 + 4) : (w_r1 + r * 33 + 1);
  float wy[16], wz[16];
#pragma unroll
  for (int k = 0; k < 16; ++k) {
    const int idx = (posi + srcoff * k) & 15;
    wy[k] = Wrow[(row << 4) | idx];
    wz[k] = Wrow[((row ^ 1) << 4) | idx];
  }

  const float wr0 = hi ? 0.0f : w_r1[r * 33];  // reward-input column
  const float bias = hi ? b_a1[r] : b_r1[r];

  // reduction coefficients
  // chain P: low -> q_raw (w_r2 . sr),  high -> c0 (w_a2 row0 . sa)
  // chain Q: low -> c1 via u (=sa),     high -> c2
  // chain R: low -> c3 via u,           high -> unused (0)
  const float cP = hi ? w_a2[r] : w_r2[r];
  const float cQ = hi ? w_a2[64 + r] : w_a2[32 + r];
  const float cR = hi ? 0.0f : w_a2[96 + r];

  const float br2 = b_r2[0];
  float ba2[4];
#pragma unroll
  for (int k = 0; k < 4; ++k) ba2[k] = b_a2[k];

  const int* __restrict__ act_b = actions + (size_t)b * T_LEN;
  const float* __restrict__ rew_b = rewards + (size_t)b * T_LEN;
  float4* __restrict__ outq = (float4*)out + (size_t)b * NT;

  const int bpi = (lane ^ 32) << 2;    // ds_bpermute byte index: lane^32

  // ---- state ----
  float x = 0.0f;                       // sr[r] (low) / sa[r] (high)
  float q0 = 0.f, q1 = 0.f, q2 = 0.f, q3 = 0.f;

  for (int t0 = 0; t0 < NT; t0 += 32) {
    int a_chunk = act_b[t0 + r];
    float r_chunk = rew_b[t0 + r];
    const int nstep = (NT - t0) < 32 ? (NT - t0) : 32;
    for (int tt = 0; tt < nstep; ++tt) {
      const int a_prev = __builtin_amdgcn_readlane(a_chunk, tt);
      const float r_prev = __int_as_float(
          __builtin_amdgcn_readlane(__float_as_int(r_chunk), tt));

      // cross-row half of the state (xor-16 within each 32-group)
      const float z = swz_xor<16>(x);

      // ---- fused matvec: low = W_r1s @ sr, high = W_a1s @ sa ----
      float acc0 = fmaf(wr0, r_prev, bias);
      float acc1 = lds_wc[(a_prev << 6) | lane];   // one-hot column / zeros
      float acc2 = 0.0f, acc3 = 0.0f;
      asm volatile("v_fmac_f32 %0, %2, %3\n\t"
                   "v_fmac_f32 %1, %4, %5"
                   : "+v"(acc0), "+v"(acc1)
                   : "v"(x), "v"(wy[0]), "v"(z), "v"(wz[0]));
      MV_ROR(acc2, acc3, 1);
      MV_ROR(acc0, acc1, 2);
      MV_ROR(acc2, acc3, 3);
      MV_ROR(acc0, acc1, 4);
      MV_ROR(acc2, acc3, 5);
      MV_ROR(acc0, acc1, 6);
      MV_ROR(acc2, acc3, 7);
      MV_ROR(acc0, acc1, 8);
      MV_ROR(acc2, acc3, 9);
      MV_ROR(acc0, acc1, 10);
      MV_ROR(acc2, acc3, 11);
      MV_ROR(acc0, acc1, 12);
      MV_ROR(acc2, acc3, 13);
      MV_ROR(acc0, acc1, 14);
      MV_ROR(acc2, acc3, 15);
      const float xn = fast_tanh((acc0 + acc2) + (acc1 + acc3));

      // ---- reductions ----
      // u: bring the other module's state to this half (lane ^ 32)
      const float u = __int_as_float(
          __builtin_amdgcn_ds_bpermute(bpi, __float_as_int(xn)));
      const float sel = hi ? xn : u;   // both halves hold sa for chains Q,R
      const float sumP = reduce32b(cP * xn);
      const float sumQ = reduce32b(cQ * sel);
      const float sumR = reduce32b(cR * sel);

      const float q_raw = __int_as_float(
          __builtin_amdgcn_readlane(__float_as_int(sumP), 0));
      const float c1s = __int_as_float(
          __builtin_amdgcn_readlane(__float_as_int(sumQ), 0));
      const float c3s = __int_as_float(
          __builtin_amdgcn_readlane(__float_as_int(sumR), 0));
      const float qn = q_raw + br2;

      // ---- q decay + chosen-arm update (valid in high lanes) ----
      q0 = (a_prev == 0) ? qn : q0 * 0.95f;
      q1 = (a_prev == 1) ? qn : q1 * 0.95f;
      q2 = (a_prev == 2) ? qn : q2 * 0.95f;
      q3 = (a_prev == 3) ? qn : q3 * 0.95f;

      if (lane == 32) {
        float4 L;
        L.x = q0 + sumP + ba2[0];   // c0 = high-group sum of chain P
        L.y = q1 + c1s + ba2[1];
        L.z = q2 + sumQ + ba2[2];   // c2 = high-group sum of chain Q
        L.w = q3 + c3s + ba2[3];
        outq[t0 + tt] = L;
      }
      x = xn;
    }
  }
}

// ---------- launch ----------

extern "C" void kernel_launch(void* const* d_in, const int* in_sizes, int n_in,
                              void* d_out, int out_size, void* d_ws,
                              size_t ws_size, hipStream_t stream) {
  const int* actions = (const int*)d_in[0];
  const float* rewards = (const float*)d_in[1];
  const float* w_r1 = (const float*)d_in[2];
  const float* b_r1 = (const float*)d_in[3];
  const float* w_r2 = (const float*)d_in[4];
  const float* b_r2 = (const float*)d_in[5];
  const float* w_a1 = (const float*)d_in[6];
  const float* b_a1 = (const float*)d_in[7];
  const float* w_a2 = (const float*)d_in[8];
  const float* b_a2 = (const float*)d_in[9];
  float* out = (float*)d_out;

  const int B = in_sizes[0] / T_LEN;     // 8192
  const int threads = 256;               // 4 waves/block, 1 batch elem/wave
  const int blocks = (B * 64) / threads; // 2048

  hipLaunchKernelGGL(memann_kernel, dim3(blocks), dim3(threads), 0, stream,
                     actions, rewards, w_r1, b_r1, w_r2, b_r2, w_a1, b_a1,
                     w_a2, b_a2, out);
}

// Round 3
// 676.322 us; speedup vs baseline: 2.4024x; 2.0499x over previous
//
#include <hip/hip_runtime.h>

#define TL 1024
#define NT 1023

typedef __bf16 bf16x8 __attribute__((ext_vector_type(8)));
typedef float  f32x4  __attribute__((ext_vector_type(4)));

__device__ __forceinline__ f32x4 mfma_bf16(bf16x8 a, bf16x8 b, f32x4 c) {
  return __builtin_amdgcn_mfma_f32_16x16x32_bf16(a, b, c, 0, 0, 0);
}

// pack bf16(e) into low16, bf16(o) into high16 (truncation)
__device__ __forceinline__ unsigned pk_hi(unsigned e, unsigned o) {
  // v_perm_b32: sel bytes 0-3 -> src1(second operand=e), 4-7 -> src0(first=o)
  return __builtin_amdgcn_perm(o, e, 0x07060302u);
}

__device__ __forceinline__ float fast_tanh(float x) {
  float e = __builtin_amdgcn_exp2f(x * 2.8853900817779268f);
  float r = __builtin_amdgcn_rcpf(e + 1.0f);
  return fmaf(-2.0f, r, 1.0f);
}

// split 8 fp32 (k-contiguous) into hi/lo bf16 fragments (truncation + residual)
__device__ __forceinline__ void split8(const float x[8], bf16x8& hi, bf16x8& lo) {
  unsigned h[4], l[4];
#pragma unroll
  for (int j = 0; j < 4; ++j) {
    unsigned eu = __float_as_uint(x[2 * j]);
    unsigned ou = __float_as_uint(x[2 * j + 1]);
    h[j] = pk_hi(eu, ou);
    float el = x[2 * j]     - __uint_as_float(eu & 0xFFFF0000u);
    float ol = x[2 * j + 1] - __uint_as_float(ou & 0xFFFF0000u);
    l[j] = pk_hi(__float_as_uint(el), __float_as_uint(ol));
  }
  hi = __builtin_bit_cast(bf16x8, make_uint4(h[0], h[1], h[2], h[3]));
  lo = __builtin_bit_cast(bf16x8, make_uint4(l[0], l[1], l[2], l[3]));
}

// ---------------------------------------------------------------------------
// One wave (64 threads) per 16 batch elements. States live as MFMA B-frags.
// Weight rows are permuted by pi(m,h)=8*(m>>2)+(m&3)+4*h so each lane's D
// registers are exactly the 8 consecutive state rows of its next B-fragment:
// no cross-lane transform between steps.
// ---------------------------------------------------------------------------
__global__ __launch_bounds__(64, 1) void memann_kernel(
    const int* __restrict__ actions, const float* __restrict__ rewards,
    const float* __restrict__ w_r1, const float* __restrict__ b_r1,
    const float* __restrict__ w_r2, const float* __restrict__ b_r2,
    const float* __restrict__ w_a1, const float* __restrict__ b_a1,
    const float* __restrict__ w_a2, const float* __restrict__ b_a2,
    float* __restrict__ out) {
  const int l  = threadIdx.x;       // 0..63
  const int b0 = blockIdx.x * 16;   // batch base for this wave
  const int m  = l & 15;            // A-frag: output-row index
  const int ga = l >> 4;            // A/B-frag: k-group (k = 8*ga + i)
  const int c  = l & 15;            // D-frag: batch column
  const int gD = l >> 4;            // D-frag: row-group (row = 4*gD + reg)

  // ---- one-time: module-A post-add table (bias + one-hot column), pi-rows --
  __shared__ __align__(16) float tbl[2][4][64][4];  // [half][action][lane][reg]
#pragma unroll
  for (int h = 0; h < 2; ++h)
#pragma unroll
    for (int a = 0; a < 4; ++a)
#pragma unroll
      for (int i = 0; i < 4; ++i) {
        const int row = 8 * gD + 4 * h + i;
        tbl[h][a][l][i] = b_a1[row] + w_a1[row * 36 + a];
      }
  __syncthreads();

  // ---- one-time: weight A-fragments (hi/lo split, pi-permuted rows) ----
  const int rowA = 8 * (m >> 2) + (m & 3);  // pi(m, 0)
  float wt[8];
  bf16x8 AWr_h[2], AWr_l[2], AWa_h[2], AWa_l[2], AQ_h, AQ_l, AC_h, AC_l;
#pragma unroll
  for (int h = 0; h < 2; ++h) {
#pragma unroll
    for (int i = 0; i < 8; ++i)
      wt[i] = w_r1[(rowA + 4 * h) * 33 + 1 + 8 * ga + i];
    split8(wt, AWr_h[h], AWr_l[h]);
#pragma unroll
    for (int i = 0; i < 8; ++i)
      wt[i] = w_a1[(rowA + 4 * h) * 36 + 4 + 8 * ga + i];
    split8(wt, AWa_h[h], AWa_l[h]);
  }
#pragma unroll
  for (int i = 0; i < 8; ++i) wt[i] = w_r2[8 * ga + i];   // all 16 rows = wr2
  split8(wt, AQ_h, AQ_l);
#pragma unroll
  for (int i = 0; i < 8; ++i) wt[i] = w_a2[(m & 3) * 32 + 8 * ga + i];
  split8(wt, AC_h, AC_l);

  // ---- one-time: module-R C-init constants (pi-rows) ----
  float br1p[8], wr0p[8];
#pragma unroll
  for (int i = 0; i < 4; ++i) {
    br1p[i]     = b_r1[8 * gD + i];
    wr0p[i]     = w_r1[(8 * gD + i) * 33];
    br1p[4 + i] = b_r1[8 * gD + 4 + i];
    wr0p[4 + i] = w_r1[(8 * gD + 4 + i) * 33];
  }
  const float br2  = b_r2[0];
  const float ba2g = b_a2[gD];

  // ---- input staging: each lane keeps its batch column's a/r, 4 steps/load
  const int*   arow = actions + (size_t)(b0 + c) * TL;
  const float* rrow = rewards + (size_t)(b0 + c) * TL;
  int4   a_cur = *(const int4*)(arow);
  float4 r_cur = *(const float4*)(rrow);
  int4   a_nxt = *(const int4*)(arow + 4);
  float4 r_nxt = *(const float4*)(rrow + 4);

  // ---- state ----
  const uint4 z4 = make_uint4(0u, 0u, 0u, 0u);
  bf16x8 Bsr_h = __builtin_bit_cast(bf16x8, z4), Bsr_l = Bsr_h;
  bf16x8 Bsa_h = Bsr_h, Bsa_l = Bsr_h;
  const f32x4 zero = {0.f, 0.f, 0.f, 0.f};
  float qv = 0.0f;                                   // q[arm = gD] of batch c
  float* outp = out + (size_t)(b0 + c) * NT * 4 + gD;

  for (int t0 = 0; t0 < TL; t0 += 4) {
#pragma unroll
    for (int u = 0; u < 4; ++u) {
      const int t = t0 + u;
      const int   a  = (u == 0) ? a_cur.x : (u == 1) ? a_cur.y
                      : (u == 2) ? a_cur.z : a_cur.w;
      const float rc = (u == 0) ? r_cur.x : (u == 1) ? r_cur.y
                      : (u == 2) ? r_cur.z : r_cur.w;

      // module-A post-add values (consumed after MFMAs -> latency hidden)
      const f32x4 pa0 = *(const f32x4*)&tbl[0][a][l][0];
      const f32x4 pa1 = *(const f32x4*)&tbl[1][a][l][0];

      // module-R C-init: bias + reward column (in registers, no LDS dep)
      f32x4 cR0, cR1;
#pragma unroll
      for (int i = 0; i < 4; ++i) {
        cR0[i] = fmaf(wr0p[i], rc, br1p[i]);
        cR1[i] = fmaf(wr0p[4 + i], rc, br1p[4 + i]);
      }

      // recurrent MFMAs: Whi*xhi + Whi*xlo + Wlo*xhi (fp32-quality)
      f32x4 dR0 = mfma_bf16(AWr_h[0], Bsr_h, cR0);
      f32x4 dR1 = mfma_bf16(AWr_h[1], Bsr_h, cR1);
      f32x4 dA0 = mfma_bf16(AWa_h[0], Bsa_h, zero);
      f32x4 dA1 = mfma_bf16(AWa_h[1], Bsa_h, zero);
      dR0 = mfma_bf16(AWr_h[0], Bsr_l, dR0);
      dR1 = mfma_bf16(AWr_h[1], Bsr_l, dR1);
      dA0 = mfma_bf16(AWa_h[0], Bsa_l, dA0);
      dA1 = mfma_bf16(AWa_h[1], Bsa_l, dA1);
      dR0 = mfma_bf16(AWr_l[0], Bsr_h, dR0);
      dR1 = mfma_bf16(AWr_l[1], Bsr_h, dR1);
      dA0 = mfma_bf16(AWa_l[0], Bsa_h, dA0);
      dA1 = mfma_bf16(AWa_l[1], Bsa_h, dA1);

      // tanh + repack into next B-fragments (pure in-lane)
      float xr[8], xa[8];
#pragma unroll
      for (int i = 0; i < 4; ++i) {
        xr[i]     = fast_tanh(dR0[i]);
        xr[4 + i] = fast_tanh(dR1[i]);
        xa[i]     = fast_tanh(dA0[i] + pa0[i]);
        xa[4 + i] = fast_tanh(dA1[i] + pa1[i]);
      }
      split8(xr, Bsr_h, Bsr_l);
      split8(xa, Bsa_h, Bsa_l);

      // head MFMAs on the NEW states: q_new (replicated rows) and c_t
      f32x4 dq = mfma_bf16(AQ_h, Bsr_h, zero);
      f32x4 dc = mfma_bf16(AC_h, Bsa_h, zero);
      dq = mfma_bf16(AQ_h, Bsr_l, dq);
      dc = mfma_bf16(AC_h, Bsa_l, dc);
      dq = mfma_bf16(AQ_l, Bsr_h, dq);
      dc = mfma_bf16(AC_l, Bsa_h, dc);

      // q decay + chosen-arm update; logits; store (lane stores arm gD)
      const float qn = dq[0] + br2;                 // every reg holds q_new[c]
      qv = (a == gD) ? qn : qv * 0.95f;
      const float cs = (gD & 2) ? ((gD & 1) ? dc[3] : dc[2])
                                : ((gD & 1) ? dc[1] : dc[0]);
      if (t < NT) outp[(size_t)t * 4] = qv + cs + ba2g;
    }
    // rotate staging, prefetch next group (clamped; in flight ~4 steps)
    a_cur = a_nxt;
    r_cur = r_nxt;
    int tp = t0 + 8;
    if (tp > TL - 4) tp = TL - 4;
    a_nxt = *(const int4*)(arow + tp);
    r_nxt = *(const float4*)(rrow + tp);
  }
}

// ---------- launch ----------

extern "C" void kernel_launch(void* const* d_in, const int* in_sizes, int n_in,
                              void* d_out, int out_size, void* d_ws,
                              size_t ws_size, hipStream_t stream) {
  const int* actions = (const int*)d_in[0];
  const float* rewards = (const float*)d_in[1];
  const float* w_r1 = (const float*)d_in[2];
  const float* b_r1 = (const float*)d_in[3];
  const float* w_r2 = (const float*)d_in[4];
  const float* b_r2 = (const float*)d_in[5];
  const float* w_a1 = (const float*)d_in[6];
  const float* b_a1 = (const float*)d_in[7];
  const float* w_a2 = (const float*)d_in[8];
  const float* b_a2 = (const float*)d_in[9];
  float* out = (float*)d_out;

  const int B = in_sizes[0] / TL;       // 8192
  const int blocks = B / 16;            // 512 waves, one per 16 batch elems

  hipLaunchKernelGGL(memann_kernel, dim3(blocks), dim3(64), 0, stream,
                     actions, rewards, w_r1, b_r1, w_r2, b_r2, w_a1, b_a1,
                     w_a2, b_a2, out);
}